// Round 11
// baseline (231.363 us; speedup 1.0000x reference)
//
#include <hip/hip_runtime.h>
#include <math.h>

// GCN 2-layer, N=100000, E=6400000, Fin=1, Fhid=16, Fout=2.
// R25 = R24 (one-block-per-bucket fusion, nbkt=256, AT=1024, 224.9us)
// with two surgical fixes:
//  1) INTERLEAVED bucketing b = dst & 255, l = dst >> 8 (391/390 nodes
//     per bucket, perfectly balanced): kills the magic-mul div chain that
//     cost k_place +8us vs R22 (54.3 vs 46.7). Cursors now cell-relative
//     so the overflow guard is just q < CAP (muls moved off the atomic
//     chain, behind the guard).
//  2) PARITY-SPLIT LDS accumulators cnt/acc[2][391], lane&1 selects copy
//     (offset precomputed per-thread, zero per-edge ops), merged in the
//     epilogue: halves same-address LDS-atomic serialization (E[pairs] =
//     64^2/(2*391) = 5.2 -> 2.6 per wave-op) - the suspected ~8us/pass
//     excess of R23/R24 fused passes over the 45us cost-model floor.
// Epilogue node index becomes strided (node = t*256 + b): ~+8MB of 32B-
// sector traffic total (~1.5us) - accepted.
// Locked-in model (R14-R24): divergent edge passes floor at ~3.3 cyc/
// active-address + ~53 cyc/wave-op per CU; 4 passes forced by the dinv
// dependency chain. Hard DON'Ts (counters on file): per-edge global
// atomics (R16 +229MB WRITE); grid.sync (R17 2.3x); __threadfence in
// edge passes (R18 x5.6); ballot dedup (R20); write-front > L2 (R21
// x5.4 amp); <=8-wave edge passes (R23).
// word = (l << 17) | src, l = dst >> 8 (0..390), src < 2^17.

#define BSZ  391      // max nodes per bucket (b<160: 391, else 390)
#define NB   256      // buckets == CUs
#define B1P  256      // place blocks; chunk = E/B1P = 25000 (/4 exact)
#define CAP  160      // slots per (bucket, place-block) cell: 640B
                      // cr ~ Binom(25000, ~391/100000): mean 97.7, sd 9.8,
                      // z = 6.3 -> P(any of 65536 cells overflows) ~ 8e-6
#define PT   512      // place threads
#define AT   1024     // fused-pass threads: 16 waves/CU
#define NWV  16       // waves per fused-pass block

// --- pass 1: sparse counting place (interleaved buckets, relative cursors)
__global__ __launch_bounds__(PT) void k_place(const int* __restrict__ src,
                                              const int* __restrict__ dst,
                                              int* __restrict__ sparse,
                                              int* __restrict__ G,
                                              int chunk) {
    __shared__ int cur[NB];
    int t = threadIdx.x, blk = blockIdx.x;
    if (t < NB) cur[t] = 0;
    __syncthreads();
    int s0 = blk * chunk, n4 = chunk >> 2;
    const int4* d4 = (const int4*)(dst + s0);
    const int4* s4 = (const int4*)(src + s0);
    for (int i = t; i < n4; i += PT) {
        int4 d = d4[i];
        int4 s = s4[i];
#pragma unroll
        for (int c = 0; c < 4; c++) {
            int dv = (c == 0) ? d.x : (c == 1) ? d.y : (c == 2) ? d.z : d.w;
            int sv = (c == 0) ? s.x : (c == 1) ? s.y : (c == 2) ? s.z : s.w;
            int b = dv & 255;              // interleaved bucket (AND)
            int l = dv >> 8;               // 0..390 (SHIFT)
            int q = atomicAdd(&cur[b], 1);
            if (q < CAP)                   // guard off the mul chain
                sparse[(b * B1P + blk) * CAP + q] = (l << 17) | sv;
        }
    }
    __syncthreads();
    if (t < NB) {
        int cnt = cur[t];
        G[t * B1P + blk] = (cnt < CAP) ? cnt : CAP;
    }
}

// --- pass 2: degree over the block's OWN bucket (parity-split counters)
//     + fused node1 epilogue: dinv = rsqrt(deg+1), y = dinv*x
__global__ __launch_bounds__(AT) void k_deg1(const int* __restrict__ sparse,
                                             const int* __restrict__ G,
                                             const float* __restrict__ x,
                                             float* __restrict__ dinv,
                                             float* __restrict__ y, int N) {
    __shared__ int cnt[2 * BSZ];
    int t = threadIdx.x, b = blockIdx.x;
    for (int i = t; i < 2 * BSZ; i += AT) cnt[i] = 0;
    __syncthreads();
    int wave = t >> 6, lane = t & 63;
    int par = (lane & 1) ? BSZ : 0;        // parity-split copy offset
    for (int c = wave; c < B1P; c += NWV) {
        int r = b * B1P + c;
        int cr = G[r];
        int base = r * CAP;
        int w[3];
        int idx = lane;
#pragma unroll
        for (int u = 0; u < 3; u++) {              // independent loads
            int off = (idx < cr) ? idx : 0;
            w[u] = sparse[base + off];
            idx += 64;
        }
        idx = lane;
#pragma unroll
        for (int u = 0; u < 3; u++) {              // then the atomics
            if (idx < cr) atomicAdd(&cnt[par + (w[u] >> 17)], 1);
            idx += 64;
        }
    }
    __syncthreads();
    if (t < BSZ) {
        int node = (t << 8) + b;           // interleaved: node = t*256 + b
        if (node < N) {
            int deg = cnt[t] + cnt[BSZ + t];
            float di = rsqrtf((float)deg + 1.0f);   // +1 self-loop
            dinv[node] = di;
            y[node] = di * x[node];
        }
    }
}

// --- pass 3: layer-1 sum (parity-split acc) + fused node2 epilogue:
//     Sv = dinv*(sum + y_self); 1->16 relu MLP; dlt = dinv*(g1-g0)
__global__ __launch_bounds__(AT) void k_agg1(const int* __restrict__ sparse,
                                             const int* __restrict__ G,
                                             const float* __restrict__ dinv,
                                             const float* __restrict__ y,
                                             const float* __restrict__ W1,
                                             const float* __restrict__ b1,
                                             const float* __restrict__ W2,
                                             float* __restrict__ dlt, int N) {
    __shared__ float acc[2 * BSZ];
    int t = threadIdx.x, b = blockIdx.x;
    for (int i = t; i < 2 * BSZ; i += AT) acc[i] = 0.f;
    __syncthreads();
    int wave = t >> 6, lane = t & 63;
    int par = (lane & 1) ? BSZ : 0;
    for (int c = wave; c < B1P; c += NWV) {
        int r = b * B1P + c;
        int cr = G[r];
        int base = r * CAP;
        int w[3]; float gv[3];
        int idx = lane;
#pragma unroll
        for (int u = 0; u < 3; u++) {              // independent loads
            int off = (idx < cr) ? idx : 0;
            w[u] = sparse[base + off];
            idx += 64;
        }
        idx = lane;
#pragma unroll
        for (int u = 0; u < 3; u++) {              // independent gathers
            int a = (idx < cr) ? (w[u] & 0x1FFFF) : 0;
            gv[u] = y[a];
            idx += 64;
        }
        idx = lane;
#pragma unroll
        for (int u = 0; u < 3; u++) {              // then the atomics
            if (idx < cr) atomicAdd(&acc[par + (w[u] >> 17)], gv[u]);
            idx += 64;
        }
    }
    __syncthreads();
    if (t < BSZ) {
        int node = (t << 8) + b;
        if (node < N) {
            float di = dinv[node];
            float Sv = di * (acc[t] + acc[BSZ + t] + y[node]);  // + self-loop
            float g0 = 0.f, g1 = 0.f;
#pragma unroll
            for (int f = 0; f < 16; f++) {
                float h = fmaxf(fmaf(W1[f], Sv, b1[f]), 0.f);
                g0 = fmaf(h, W2[2 * f], g0);
                g1 = fmaf(h, W2[2 * f + 1], g1);
            }
            dlt[node] = di * (g1 - g0);    // premultiplied by dinv[src]
        }
    }
}

// --- pass 4: layer-2 sum of dlt (parity-split acc) + fused out epilogue:
//     stable 2-class log_softmax from d = z1 - z0
__global__ __launch_bounds__(AT) void k_agg2(const int* __restrict__ sparse,
                                             const int* __restrict__ G,
                                             const float* __restrict__ dinv,
                                             const float* __restrict__ dlt,
                                             const float* __restrict__ b2,
                                             float2* __restrict__ out, int N) {
    __shared__ float acc[2 * BSZ];
    int t = threadIdx.x, b = blockIdx.x;
    for (int i = t; i < 2 * BSZ; i += AT) acc[i] = 0.f;
    __syncthreads();
    int wave = t >> 6, lane = t & 63;
    int par = (lane & 1) ? BSZ : 0;
    for (int c = wave; c < B1P; c += NWV) {
        int r = b * B1P + c;
        int cr = G[r];
        int base = r * CAP;
        int w[3]; float gv[3];
        int idx = lane;
#pragma unroll
        for (int u = 0; u < 3; u++) {
            int off = (idx < cr) ? idx : 0;
            w[u] = sparse[base + off];
            idx += 64;
        }
        idx = lane;
#pragma unroll
        for (int u = 0; u < 3; u++) {
            int a = (idx < cr) ? (w[u] & 0x1FFFF) : 0;
            gv[u] = dlt[a];
            idx += 64;
        }
        idx = lane;
#pragma unroll
        for (int u = 0; u < 3; u++) {
            if (idx < cr) atomicAdd(&acc[par + (w[u] >> 17)], gv[u]);
            idx += 64;
        }
    }
    __syncthreads();
    if (t < BSZ) {
        int node = (t << 8) + b;
        if (node < N) {
            float d = dinv[node] * (acc[t] + acc[BSZ + t] + dlt[node])
                      + (b2[1] - b2[0]);
            float o0, o1;
            if (d > 0.f) {
                float e = expf(-d);
                o0 = -d - log1pf(e);
                o1 = -log1pf(e);
            } else {
                float e = expf(d);
                o0 = -log1pf(e);
                o1 = d - log1pf(e);
            }
            out[node] = make_float2(o0, o1);
        }
    }
}

extern "C" void kernel_launch(void* const* d_in, const int* in_sizes, int n_in,
                              void* d_out, int out_size, void* d_ws, size_t ws_size,
                              hipStream_t stream) {
    const float* x  = (const float*)d_in[0];
    const int* ei   = (const int*)d_in[1];
    const float* W1 = (const float*)d_in[2];
    const float* b1 = (const float*)d_in[3];
    const float* W2 = (const float*)d_in[4];
    const float* b2 = (const float*)d_in[5];

    const int N = in_sizes[0];        // 100000
    const int E = in_sizes[1] / 2;    // 6400000
    const int* src = ei;
    const int* dst = ei + E;

    const int chunk = E / B1P;        // 25000 (/4 exact)
    const int NREG  = NB * B1P;       // 65536 cells

    // ws (ints): sparse[NREG*CAP] 41.9MB | G[NREG] 0.26MB |
    //            dinv[N] | y[N] | dlt[N]                  (~43.4 MB)
    int* sparse = (int*)d_ws;
    int* G      = sparse + (size_t)NREG * CAP;
    float* dinv = (float*)(G + NREG);
    float* y    = dinv + N;
    float* dlt  = y + N;

    k_place <<<B1P, PT, 0, stream>>>(src, dst, sparse, G, chunk);
    k_deg1  <<<NB,  AT, 0, stream>>>(sparse, G, x, dinv, y, N);
    k_agg1  <<<NB,  AT, 0, stream>>>(sparse, G, dinv, y, W1, b1, W2, dlt, N);
    k_agg2  <<<NB,  AT, 0, stream>>>(sparse, G, dinv, dlt, b2,
                                     (float2*)d_out, N);
}

// Round 12
// 222.673 us; speedup vs baseline: 1.0390x; 1.0390x over previous
//
#include <hip/hip_runtime.h>
#include <math.h>

// GCN 2-layer, N=100000, E=6400000, Fin=1, Fhid=16, Fout=2.
// R26 = REVERT to R22 (222.7us, session best). 11 rounds / 5 structural
// families mapped the landscape:
//   R22 split-bucket 7-kernel: 222.7  <- best (this file)
//   R24 ownership 4-kernel fusion: 224.9 (passes +9us each; saves nodes+
//        gaps ~24us - a wash). R25 micro-fixes on it: 231 (both nulls).
//   R15 CSR 267 / R16 global-atomics 444 / R17 cooperative 627 /
//   R18 tickets+fence 766 / R21 tiny-buckets 271.
// Locked model: divergent wave64 LDS-atomic/gather edge passes run at
// ~4.5 cyc/CU/edge (throughput wall; immune to ILP batching R22, 16-wave
// occupancy R24, ballot dedup R20, parity split R25). The dinv dependency
// chain (sym-norm: sum dinv[src]*x[src] not separable) forces 4 passes =
// ~178us of walls. Remaining ~36us = node kernels + 6 dispatch gaps;
// every fusion mechanism that removes them costs >= as much in pass
// slowdown (counters on file per family). This is the structural floor:
// pre-registered, if this reproduces 222+-3us -> declare ROOFLINE.
// word = (dst&1023)<<17 | src  (src < 2^17).

#define CSH   10
#define CMASK 1023
#define C     1024
#define B1P   256      // place blocks; chunk = E/B1P = 25000 (/4 exact)
#define CAP   384      // slots per (bucket, block) cell (mean 255, +8sigma)
#define GF    768      // deg/agg blocks: exactly 3 per CU
#define AT    512      // threads for deg/agg
#define PT    512      // place threads (2 waves/SIMD)

// --- pass 1: sparse counting place
__global__ __launch_bounds__(PT) void k_place(const int* __restrict__ src,
                                              const int* __restrict__ dst,
                                              int* __restrict__ sparse,
                                              int* __restrict__ G,
                                              int chunk, int nbkt) {
    __shared__ int cur[128];
    int t = threadIdx.x, blk = blockIdx.x;
    if (t < nbkt) cur[t] = t * (B1P * CAP) + blk * CAP;
    __syncthreads();
    int s0 = blk * chunk, n4 = chunk >> 2;
    const int4* d4 = (const int4*)(dst + s0);
    const int4* s4 = (const int4*)(src + s0);
    for (int i = t; i < n4; i += PT) {
        int4 d = d4[i];
        int4 s = s4[i];
        int b, q;
        b = d.x >> CSH; q = atomicAdd(&cur[b], 1);
        if (q < b * (B1P * CAP) + blk * CAP + CAP) sparse[q] = ((d.x & CMASK) << 17) | s.x;
        b = d.y >> CSH; q = atomicAdd(&cur[b], 1);
        if (q < b * (B1P * CAP) + blk * CAP + CAP) sparse[q] = ((d.y & CMASK) << 17) | s.y;
        b = d.z >> CSH; q = atomicAdd(&cur[b], 1);
        if (q < b * (B1P * CAP) + blk * CAP + CAP) sparse[q] = ((d.z & CMASK) << 17) | s.z;
        b = d.w >> CSH; q = atomicAdd(&cur[b], 1);
        if (q < b * (B1P * CAP) + blk * CAP + CAP) sparse[q] = ((d.w & CMASK) << 17) | s.w;
    }
    __syncthreads();
    if (t < nbkt) {
        int cnt = cur[t] - (t * (B1P * CAP) + blk * CAP);
        G[t * B1P + blk] = (cnt < CAP) ? cnt : CAP;
    }
}

// block g -> (bucket b, split s, nsplits Sb). First `rem` buckets have
// q+1 splits, the rest q.  (q=7, rem=82 for N=100000 -> GF=768.)
__device__ __forceinline__ void blk_map(int g, int q, int rem,
                                        int& b, int& s, int& Sb) {
    int cut = rem * (q + 1);
    if (g < cut) { b = g / (q + 1); s = g - b * (q + 1); Sb = q + 1; }
    else { int h = g - cut; b = rem + h / q; s = h - (h / q) * q; Sb = q; }
}

// --- per-node degree partials: 6-wide batched loads, then atomics
__global__ __launch_bounds__(AT) void k_deg(const int* __restrict__ sparse,
                                            const int* __restrict__ G,
                                            int* __restrict__ Pdeg,
                                            int q, int rem) {
    __shared__ int cnt[C];
    int t = threadIdx.x, g = blockIdx.x;
    int b, s, Sb; blk_map(g, q, rem, b, s, Sb);
    cnt[t] = 0; cnt[t + AT] = 0;
    __syncthreads();
    int wave = t >> 6, lane = t & 63;
    for (int m = wave;; m += 8) {
        int c = s + m * Sb;
        if (c >= B1P) break;
        int r = b * B1P + c;
        int cr = G[r];
        int base = r * CAP;
        int w[6];
        int idx = lane;
#pragma unroll
        for (int u = 0; u < 6; u++) {              // 6 independent loads
            int off = (idx < cr) ? idx : 0;
            w[u] = sparse[base + off];
            idx += 64;
        }
        idx = lane;
#pragma unroll
        for (int u = 0; u < 6; u++) {              // then the atomics
            if (idx < cr) atomicAdd(&cnt[w[u] >> 17], 1);
            idx += 64;
        }
    }
    __syncthreads();
    Pdeg[(size_t)g * C + t] = cnt[t];
    Pdeg[(size_t)g * C + t + AT] = cnt[t + AT];
}

// --- nodes: deg -> dinv, y = dinv * x
__global__ __launch_bounds__(256) void k_node1(const int* __restrict__ Pdeg,
                                               const float* __restrict__ x,
                                               float* __restrict__ dinv,
                                               float* __restrict__ y,
                                               int q, int rem, int N) {
    int node = blockIdx.x * 256 + threadIdx.x;
    if (node >= N) return;
    int b = node >> CSH, l = node & CMASK;
    int off = (b < rem) ? b * (q + 1) : rem * (q + 1) + (b - rem) * q;
    int cnt = (b < rem) ? q + 1 : q;
    const int* base = Pdeg + (size_t)off * C + l;
    int deg = 0;
    for (int s = 0; s < cnt; s++) deg += base[(size_t)s * C];
    float di = rsqrtf((float)deg + 1.0f);   // +1 self-loop
    dinv[node] = di;
    y[node] = di * x[node];
}

// --- layer-1 partials: batched loads -> batched gathers -> atomics
__global__ __launch_bounds__(AT) void k_agg1(const int* __restrict__ sparse,
                                             const int* __restrict__ G,
                                             const float* __restrict__ y,
                                             float* __restrict__ P1,
                                             int q, int rem) {
    __shared__ float acc[C];
    int t = threadIdx.x, g = blockIdx.x;
    int b, s, Sb; blk_map(g, q, rem, b, s, Sb);
    acc[t] = 0.f; acc[t + AT] = 0.f;
    __syncthreads();
    int wave = t >> 6, lane = t & 63;
    for (int m = wave;; m += 8) {
        int c = s + m * Sb;
        if (c >= B1P) break;
        int r = b * B1P + c;
        int cr = G[r];
        int base = r * CAP;
        int w[6]; float gv[6];
        int idx = lane;
#pragma unroll
        for (int u = 0; u < 6; u++) {              // 6 independent loads
            int off = (idx < cr) ? idx : 0;
            w[u] = sparse[base + off];
            idx += 64;
        }
        idx = lane;
#pragma unroll
        for (int u = 0; u < 6; u++) {              // 6 independent gathers
            int a = (idx < cr) ? (w[u] & 0x1FFFF) : 0;
            gv[u] = y[a];
            idx += 64;
        }
        idx = lane;
#pragma unroll
        for (int u = 0; u < 6; u++) {              // then the atomics
            if (idx < cr) atomicAdd(&acc[w[u] >> 17], gv[u]);
            idx += 64;
        }
    }
    __syncthreads();
    P1[(size_t)g * C + t] = acc[t];
    P1[(size_t)g * C + t + AT] = acc[t + AT];
}

// --- nodes: layer-1 finish + fused 1->16 relu MLP -> 16->2, emit scalar
//     delta[node] = dinv * (g1 - g0)   (log_softmax needs only z1-z0)
__global__ __launch_bounds__(256) void k_node2(const float* __restrict__ P1,
                                               const float* __restrict__ dinv,
                                               const float* __restrict__ y,
                                               const float* __restrict__ W1,
                                               const float* __restrict__ b1,
                                               const float* __restrict__ W2,
                                               float* __restrict__ dlt,
                                               int q, int rem, int N) {
    int node = blockIdx.x * 256 + threadIdx.x;
    if (node >= N) return;
    int b = node >> CSH, l = node & CMASK;
    int off = (b < rem) ? b * (q + 1) : rem * (q + 1) + (b - rem) * q;
    int cnt = (b < rem) ? q + 1 : q;
    const float* base = P1 + (size_t)off * C + l;
    float sum = 0.f;
    for (int s = 0; s < cnt; s++) sum += base[(size_t)s * C];
    float di = dinv[node];
    float Sv = di * (sum + y[node]);        // self-loop adds y[node]
    float g0 = 0.f, g1 = 0.f;
#pragma unroll
    for (int f = 0; f < 16; f++) {
        float h = fmaxf(fmaf(W1[f], Sv, b1[f]), 0.f);
        g0 = fmaf(h, W2[2 * f], g0);
        g1 = fmaf(h, W2[2 * f + 1], g1);
    }
    dlt[node] = di * (g1 - g0);             // premultiplied by dinv[src]
}

// --- layer-2 partials of the scalar delta: same batching
__global__ __launch_bounds__(AT) void k_agg2d(const int* __restrict__ sparse,
                                              const int* __restrict__ G,
                                              const float* __restrict__ dlt,
                                              float* __restrict__ P2,
                                              int q, int rem) {
    __shared__ float acc[C];
    int t = threadIdx.x, g = blockIdx.x;
    int b, s, Sb; blk_map(g, q, rem, b, s, Sb);
    acc[t] = 0.f; acc[t + AT] = 0.f;
    __syncthreads();
    int wave = t >> 6, lane = t & 63;
    for (int m = wave;; m += 8) {
        int c = s + m * Sb;
        if (c >= B1P) break;
        int r = b * B1P + c;
        int cr = G[r];
        int base = r * CAP;
        int w[6]; float gv[6];
        int idx = lane;
#pragma unroll
        for (int u = 0; u < 6; u++) {
            int off = (idx < cr) ? idx : 0;
            w[u] = sparse[base + off];
            idx += 64;
        }
        idx = lane;
#pragma unroll
        for (int u = 0; u < 6; u++) {
            int a = (idx < cr) ? (w[u] & 0x1FFFF) : 0;
            gv[u] = dlt[a];
            idx += 64;
        }
        idx = lane;
#pragma unroll
        for (int u = 0; u < 6; u++) {
            if (idx < cr) atomicAdd(&acc[w[u] >> 17], gv[u]);
            idx += 64;
        }
    }
    __syncthreads();
    P2[(size_t)g * C + t] = acc[t];
    P2[(size_t)g * C + t + AT] = acc[t + AT];
}

// --- nodes: d = di*(sum + delta_self) + (b2[1]-b2[0]); stable 2-class
//     log_softmax from the difference alone
__global__ __launch_bounds__(256) void k_out(const float* __restrict__ P2,
                                             const float* __restrict__ dinv,
                                             const float* __restrict__ dlt,
                                             const float* __restrict__ b2,
                                             float2* __restrict__ out,
                                             int q, int rem, int N) {
    int node = blockIdx.x * 256 + threadIdx.x;
    if (node >= N) return;
    int b = node >> CSH, l = node & CMASK;
    int off = (b < rem) ? b * (q + 1) : rem * (q + 1) + (b - rem) * q;
    int cnt = (b < rem) ? q + 1 : q;
    const float* base = P2 + (size_t)off * C + l;
    float sum = 0.f;
    for (int s = 0; s < cnt; s++) sum += base[(size_t)s * C];
    float d = dinv[node] * (sum + dlt[node]) + (b2[1] - b2[0]);  // z1 - z0
    float o0, o1;
    if (d > 0.f) {
        float e = expf(-d);
        o0 = -d - log1pf(e);
        o1 = -log1pf(e);
    } else {
        float e = expf(d);
        o0 = -log1pf(e);
        o1 = d - log1pf(e);
    }
    out[node] = make_float2(o0, o1);
}

extern "C" void kernel_launch(void* const* d_in, const int* in_sizes, int n_in,
                              void* d_out, int out_size, void* d_ws, size_t ws_size,
                              hipStream_t stream) {
    const float* x  = (const float*)d_in[0];
    const int* ei   = (const int*)d_in[1];
    const float* W1 = (const float*)d_in[2];
    const float* b1 = (const float*)d_in[3];
    const float* W2 = (const float*)d_in[4];
    const float* b2 = (const float*)d_in[5];

    const int N = in_sizes[0];        // 100000
    const int E = in_sizes[1] / 2;    // 6400000
    const int* src = ei;
    const int* dst = ei + E;

    const int nbkt  = (N + CMASK) >> CSH;    // 98
    const int chunk = E / B1P;               // 25000
    const int NREG  = nbkt * B1P;            // 25088 cells
    const int np    = nbkt << CSH;           // 100352 padded nodes
    const int gN    = (N + 255) / 256;       // 391

    const int q   = GF / nbkt;               // 7
    const int rem = GF - nbkt * q;           // 82

    // ws (ints): sparse[NREG*CAP] 38.5MB | G[NREG] | Pbuf[GF*C] 3.1MB |
    //            dinv[np] | y[np] | dlt[np]   (~43 MB)
    int* sparse = (int*)d_ws;
    int* G      = sparse + (size_t)NREG * CAP;
    int* Pbuf   = G + NREG;
    float* dinv = (float*)(Pbuf + (size_t)GF * C);
    float* y    = dinv + np;
    float* dlt  = y + np;

    k_place <<<B1P, PT,  0, stream>>>(src, dst, sparse, G, chunk, nbkt);
    k_deg   <<<GF,  AT,  0, stream>>>(sparse, G, Pbuf, q, rem);
    k_node1 <<<gN,  256, 0, stream>>>(Pbuf, x, dinv, y, q, rem, N);
    k_agg1  <<<GF,  AT,  0, stream>>>(sparse, G, y, (float*)Pbuf, q, rem);
    k_node2 <<<gN,  256, 0, stream>>>((const float*)Pbuf, dinv, y, W1, b1, W2,
                                      dlt, q, rem, N);
    k_agg2d <<<GF,  AT,  0, stream>>>(sparse, G, dlt, (float*)Pbuf, q, rem);
    k_out   <<<gN,  256, 0, stream>>>((const float*)Pbuf, dinv, dlt, b2,
                                      (float2*)d_out, q, rem, N);
}